// Round 7
// baseline (192.024 us; speedup 1.0000x reference)
//
#include <hip/hip_runtime.h>
#include <hip/hip_bf16.h>

typedef __hip_bfloat16 bf16;
typedef __attribute__((ext_vector_type(8))) short short8;   // 8 bf16 = one MFMA A/B frag
typedef __attribute__((ext_vector_type(4))) float f32x4;    // MFMA C/D frag

#define MFMA(a, b, c) __builtin_amdgcn_mfma_f32_16x16x32_bf16(a, b, c, 0, 0, 0)

static __device__ __forceinline__ float b2f(unsigned short u) {
  union { unsigned u; float f; } t; t.u = ((unsigned)u) << 16; return t.f;
}
static __device__ __forceinline__ unsigned short f2bf(float f) {
  union { float f; unsigned u; } t; t.f = f;
  unsigned r = t.u + 0x7fffu + ((t.u >> 16) & 1u);   // RNE
  return (unsigned short)(r >> 16);
}
static __device__ __forceinline__ unsigned pack2(float a, float b) {
  return (unsigned)f2bf(a) | ((unsigned)f2bf(b) << 16);
}

// ---- workspace layout (bf16 element offsets) ----
#define KB_OFF   ((size_t)0)          // K  [2048][1024]
#define QB_OFF   ((size_t)2097152)    // Q  [2048][1024]
#define G1_OFF   ((size_t)4194304)    // G1 [2048][1024]
#define G2_OFF   ((size_t)6291456)    // G2 [2048][1024]
#define VT_OFF   ((size_t)8388608)    // V^T [512][2048]
#define WT_BASE  ((size_t)9437184)
#define WTK_OFF  (WT_BASE)                       // [1024][512]
#define WTQ_OFF  (WT_BASE + (size_t)524288)
#define WTG1_OFF (WT_BASE + (size_t)1048576)
#define WTG2_OFF (WT_BASE + (size_t)1572864)
#define WTV_OFF  (WT_BASE + (size_t)2097152)     // [512][512]
// After proj, WT region is dead -> reuse for attention partials (n-split 2):
#define NUM0_OFF (WT_BASE)                        // bf16 [2048][512]
#define NUM1_OFF (WT_BASE + (size_t)1048576)      // bf16 [2048][512]
#define DEN_OFF  (WT_BASE + (size_t)2097152)      // f32 [2][8][2048]
#define VSUM_OFF (WT_BASE + (size_t)2162688)      // f32 [512]
// total ws: 11,600,896 bf16 elems = 23.2 MB (< round-6's proven 25.4 MB)

// Transpose + convert W[k][n] fp32 -> Wt[n][k] bf16, all 5 weights in one launch.
__global__ __launch_bounds__(256)
void wtrans_kernel(const float* __restrict__ WK, const float* __restrict__ WQ,
                   const float* __restrict__ WG1, const float* __restrict__ WG2,
                   const float* __restrict__ WV, bf16* __restrict__ ws)
{
  __shared__ float T[32][33];
  const float* W; unsigned short* Wt; int N;
  switch (blockIdx.z) {
    case 0:  W = WK;  Wt = (unsigned short*)(ws + WTK_OFF);  N = 1024; break;
    case 1:  W = WQ;  Wt = (unsigned short*)(ws + WTQ_OFF);  N = 1024; break;
    case 2:  W = WG1; Wt = (unsigned short*)(ws + WTG1_OFF); N = 1024; break;
    case 3:  W = WG2; Wt = (unsigned short*)(ws + WTG2_OFF); N = 1024; break;
    default: W = WV;  Wt = (unsigned short*)(ws + WTV_OFF);  N = 512;  break;
  }
  int n0 = blockIdx.x * 32, k0 = blockIdx.y * 32;
  if (n0 >= N) return;
  int tid = threadIdx.x;
  int kk = tid >> 3, nn = (tid & 7) * 4;
  float4 v = *(const float4*)(W + (size_t)(k0 + kk) * N + n0 + nn);
  T[kk][nn] = v.x; T[kk][nn + 1] = v.y; T[kk][nn + 2] = v.z; T[kk][nn + 3] = v.w;
  __syncthreads();
  int n2 = tid >> 3, k2 = (tid & 7) * 4;
  uint2 pw;
  pw.x = pack2(T[k2][n2],     T[k2 + 1][n2]);
  pw.y = pack2(T[k2 + 2][n2], T[k2 + 3][n2]);
  *(uint2*)(Wt + (size_t)(n0 + n2) * 512 + k0 + k2) = pw;
}

// Batched MFMA projection GEMM (verified round 4).
__global__ __launch_bounds__(256)
void proj_mfma_kernel(const float* __restrict__ fa, const float* __restrict__ fp,
                      const float* __restrict__ sa, const float* __restrict__ sp,
                      const float* __restrict__ bKp, const float* __restrict__ bQp,
                      const float* __restrict__ bG1p, const float* __restrict__ bG2p,
                      const float* __restrict__ bVp, bf16* __restrict__ ws)
{
  __shared__ short Xs[128][40];
  __shared__ short Wsh[128][40];
  const float* X; const unsigned short* Wt; const float* bias; unsigned short* C;
  int N; bool trans = false;
  switch (blockIdx.z) {
    case 0:  X = fa; Wt = (const unsigned short*)(ws + WTK_OFF);  bias = bKp;  C = (unsigned short*)(ws + KB_OFF); N = 1024; break;
    case 1:  X = sa; Wt = (const unsigned short*)(ws + WTQ_OFF);  bias = bQp;  C = (unsigned short*)(ws + QB_OFF); N = 1024; break;
    case 2:  X = fp; Wt = (const unsigned short*)(ws + WTG1_OFF); bias = bG1p; C = (unsigned short*)(ws + G1_OFF); N = 1024; break;
    case 3:  X = sp; Wt = (const unsigned short*)(ws + WTG2_OFF); bias = bG2p; C = (unsigned short*)(ws + G2_OFF); N = 1024; break;
    default: X = fa; Wt = (const unsigned short*)(ws + WTV_OFF);  bias = bVp;  C = (unsigned short*)(ws + VT_OFF); N = 512; trans = true; break;
  }
  const int n0 = blockIdx.x * 128;
  if (n0 >= N) return;
  const int m0 = blockIdx.y * 128;
  const int tid = threadIdx.x;
  const int w = tid >> 6, l = tid & 63, l15 = l & 15, l4 = l >> 4;
  const int wm = (w & 1) * 64, wn = (w >> 1) * 64;
  const int srow = tid >> 1, shalf = (tid & 1) * 16;

  const float* xp = X + (size_t)(m0 + srow) * 512 + shalf;
  const unsigned short* wp = Wt + (size_t)(n0 + srow) * 512 + shalf;

  const f32x4 zero = {0.f, 0.f, 0.f, 0.f};
  f32x4 acc[4][4];
#pragma unroll
  for (int i = 0; i < 4; ++i)
#pragma unroll
    for (int j = 0; j < 4; ++j) acc[i][j] = zero;

  float4 px[4]; uint4 pw0, pw1;
  auto ldg = [&](int kc) {
    px[0] = *(const float4*)(xp + kc);
    px[1] = *(const float4*)(xp + kc + 4);
    px[2] = *(const float4*)(xp + kc + 8);
    px[3] = *(const float4*)(xp + kc + 12);
    pw0 = *(const uint4*)(wp + kc);
    pw1 = *(const uint4*)(wp + kc + 8);
  };
  ldg(0);

  for (int kc = 0; kc < 512; kc += 32) {
    __syncthreads();
    uint4 xa, xb;
    xa.x = pack2(px[0].x, px[0].y); xa.y = pack2(px[0].z, px[0].w);
    xa.z = pack2(px[1].x, px[1].y); xa.w = pack2(px[1].z, px[1].w);
    xb.x = pack2(px[2].x, px[2].y); xb.y = pack2(px[2].z, px[2].w);
    xb.z = pack2(px[3].x, px[3].y); xb.w = pack2(px[3].z, px[3].w);
    *(uint4*)&Xs[srow][shalf]      = xa;
    *(uint4*)&Xs[srow][shalf + 8]  = xb;
    *(uint4*)&Wsh[srow][shalf]     = pw0;
    *(uint4*)&Wsh[srow][shalf + 8] = pw1;
    __syncthreads();
    if (kc + 32 < 512) ldg(kc + 32);

    short8 xf[4], wf[4];
#pragma unroll
    for (int t = 0; t < 4; ++t) {
      xf[t] = *(const short8*)&Xs[wm + t * 16 + l15][l4 * 8];
      wf[t] = *(const short8*)&Wsh[wn + t * 16 + l15][l4 * 8];
    }
    if (!trans) {
#pragma unroll
      for (int i = 0; i < 4; ++i)
#pragma unroll
        for (int j = 0; j < 4; ++j)
          acc[i][j] = MFMA(wf[i], xf[j], acc[i][j]);   // D[n][m]
    } else {
#pragma unroll
      for (int i = 0; i < 4; ++i)
#pragma unroll
        for (int j = 0; j < 4; ++j)
          acc[i][j] = MFMA(xf[i], wf[j], acc[i][j]);   // D[m][n]
    }
  }

  if (!trans) {
#pragma unroll
    for (int tn = 0; tn < 4; ++tn) {
      float4 b4 = *(const float4*)(bias + n0 + wn + tn * 16 + l4 * 4);
#pragma unroll
      for (int tm = 0; tm < 4; ++tm) {
        uint2 pw;
        pw.x = pack2(acc[tn][tm][0] + b4.x, acc[tn][tm][1] + b4.y);
        pw.y = pack2(acc[tn][tm][2] + b4.z, acc[tn][tm][3] + b4.w);
        *(uint2*)(C + (size_t)(m0 + wm + tm * 16 + l15) * N + n0 + wn + tn * 16 + l4 * 4) = pw;
      }
    }
  } else {
#pragma unroll
    for (int tn = 0; tn < 4; ++tn) {
      float bn = bias[n0 + wn + tn * 16 + l15];
#pragma unroll
      for (int tm = 0; tm < 4; ++tm) {
        uint2 pw;
        pw.x = pack2(acc[tm][tn][0] + bn, acc[tm][tn][1] + bn);
        pw.y = pack2(acc[tm][tn][2] + bn, acc[tm][tn][3] + bn);
        *(uint2*)(C + (size_t)(n0 + wn + tn * 16 + l15) * 2048 + m0 + wm + tm * 16 + l4 * 4) = pw;
      }
    }
  }
}

// Vsum[c] = sum_n V[n][c] (read V^T rows). 8 blocks x 256 thr; 4 thr per c.
__global__ __launch_bounds__(256)
void vsum_kernel(const bf16* __restrict__ ws_vt, float* __restrict__ vs)
{
  int tid = threadIdx.x;
  int c = blockIdx.x * 64 + (tid >> 2);
  int q = tid & 3;
  const unsigned short* vp = (const unsigned short*)ws_vt + (size_t)c * 2048 + q * 512;
  float s = 0.f;
  for (int i = 0; i < 512; i += 8) {
    short8 v = *(const short8*)(vp + i);
#pragma unroll
    for (int j = 0; j < 8; ++j) s += b2f((unsigned short)v[j]);
  }
  s += __shfl_xor(s, 1, 64);
  s += __shfl_xor(s, 2, 64);
  if (q == 0) vs[c] = s;
}

// MFMA fused attention, m=32 per wave (2 fragment sets) -> halves the dominant
// LDS term (score B-frag reads amortized over 2x m-rows). Block = 4 waves x
// m32 = 128 rows; grid (16, 8, 2), n-split 2 (16 iters of 64).
__global__ __launch_bounds__(256)
void attn_mfma_kernel(const bf16* __restrict__ Kb, const bf16* __restrict__ G1b,
                      const bf16* __restrict__ Vtg, const bf16* __restrict__ Qb,
                      const bf16* __restrict__ G2b, bf16* __restrict__ ws)
{
  __shared__ short Ks[64][136];    // stride 272B = 17 quads: balanced b128
  __shared__ short G1s[64][136];
  __shared__ short Vts[64][72];    // V^T[j][n], stride 144B
  __shared__ short Pr[4][32][72];  // per-wave P row-major [m 0..31][n]
  // LDS total = 17408*2 + 9216 + 18432 = 62464 B

  const int tid = threadIdx.x;
  const int w   = tid >> 6;
  const int l   = tid & 63;
  const int l15 = l & 15;
  const int l4  = l >> 4;
  const int h   = blockIdx.y;
  const int m0  = blockIdx.x * 128;
  const int split = blockIdx.z;

  // ---- persistent Q/G2 A-fragments: 2 sets (rows w*32 + s*16 + l15) ----
  short8 qf[2][4], gf[2][4];
#pragma unroll
  for (int s = 0; s < 2; ++s) {
    const size_t ro = (size_t)(m0 + w * 32 + s * 16 + l15) * 1024 + h * 128 + l4 * 8;
#pragma unroll
    for (int kk = 0; kk < 4; ++kk) {
      qf[s][kk] = *(const short8*)(Qb + ro + kk * 32);
      gf[s][kk] = *(const short8*)(G2b + ro + kk * 32);
    }
  }
  // ---- row norms -> per-row scale, broadcast to C/D row positions ----
  float s4[2][4];
#pragma unroll
  for (int s = 0; s < 2; ++s) {
    float sq = 0.f, sg = 0.f;
#pragma unroll
    for (int kk = 0; kk < 4; ++kk)
#pragma unroll
      for (int j = 0; j < 8; ++j) {
        float q = b2f((unsigned short)qf[s][kk][j]);
        float g = b2f((unsigned short)gf[s][kk][j]);
        sq += q * q; sg += g * g;
      }
    sq += __shfl_xor(sq, 16, 64); sq += __shfl_xor(sq, 32, 64);
    sg += __shfl_xor(sg, 16, 64); sg += __shfl_xor(sg, 32, 64);
    float sc = rsqrtf(sq) * rsqrtf(sg) * (1.0f / 16384.0f);
#pragma unroll
    for (int r = 0; r < 4; ++r) s4[s][r] = __shfl(sc, l4 * 4 + r, 64);
  }

  const int r0 = tid >> 3, c0 = (tid & 7) * 16;   // K/G1 staging map
  const int jv = tid >> 2, nv = (tid & 3) * 16;   // Vt staging map

  short8 pk[4], pg[4], pv0, pv1;
  auto load_tile = [&](int nt) {       // nt in global 64-units
    const int n0 = nt * 64;
    const bf16* kp = Kb  + (size_t)(n0 + r0) * 1024 + h * 128 + c0;
    const bf16* gp = G1b + (size_t)(n0 + r0) * 1024 + h * 128 + c0;
    pk[0] = *(const short8*)(kp);
    pk[1] = *(const short8*)(kp + 8);
    pk[2] = *(const short8*)(kp + 32 * 1024);
    pk[3] = *(const short8*)(kp + 32 * 1024 + 8);
    pg[0] = *(const short8*)(gp);
    pg[1] = *(const short8*)(gp + 8);
    pg[2] = *(const short8*)(gp + 32 * 1024);
    pg[3] = *(const short8*)(gp + 32 * 1024 + 8);
    const bf16* vp = Vtg + (size_t)(h * 64 + jv) * 2048 + n0 + nv;
    pv0 = *(const short8*)(vp);
    pv1 = *(const short8*)(vp + 8);
  };
  const int ntbase = split * 16;
  load_tile(ntbase);

  const f32x4 zero = {0.f, 0.f, 0.f, 0.f};
  f32x4 accO[2][4], accD[2] = {zero, zero};
#pragma unroll
  for (int s = 0; s < 2; ++s)
#pragma unroll
    for (int t = 0; t < 4; ++t) accO[s][t] = zero;

  short8 ones;
#pragma unroll
  for (int j = 0; j < 8; ++j) ones[j] = (short)0x3F80;  // bf16 1.0

  for (int nt = 0; nt < 16; ++nt) {
    __syncthreads();
    *(short8*)&Ks[r0][c0]           = pk[0];
    *(short8*)&Ks[r0][c0 + 8]       = pk[1];
    *(short8*)&Ks[r0 + 32][c0]      = pk[2];
    *(short8*)&Ks[r0 + 32][c0 + 8]  = pk[3];
    *(short8*)&G1s[r0][c0]          = pg[0];
    *(short8*)&G1s[r0][c0 + 8]      = pg[1];
    *(short8*)&G1s[r0 + 32][c0]     = pg[2];
    *(short8*)&G1s[r0 + 32][c0 + 8] = pg[3];
    *(short8*)&Vts[jv][nv]          = pv0;
    *(short8*)&Vts[jv][nv + 8]      = pv1;
    __syncthreads();
    if (nt + 1 < 16) load_tile(ntbase + nt + 1);   // prefetch overlaps compute

    // ---- scores: each K/G1 B-frag read feeds 2 MFMAs (2 m-sets) ----
#pragma unroll
    for (int t = 0; t < 4; ++t) {
      f32x4 sa0 = zero, sa1 = zero, sg0 = zero, sg1 = zero;
#pragma unroll
      for (int kk = 0; kk < 4; ++kk) {
        short8 kbf = *(const short8*)&Ks[t * 16 + l15][kk * 32 + l4 * 8];
        sa0 = MFMA(qf[0][kk], kbf, sa0);
        sa1 = MFMA(qf[1][kk], kbf, sa1);
        short8 gbf = *(const short8*)&G1s[t * 16 + l15][kk * 32 + l4 * 8];
        sg0 = MFMA(gf[0][kk], gbf, sg0);
        sg1 = MFMA(gf[1][kk], gbf, sg1);
      }
      // P' = x + x^2/2 (|x|~1e-4), bf16, per-wave row-major scratch
#pragma unroll
      for (int r = 0; r < 4; ++r) {
        float x0 = sa0[r] * sg0[r] * s4[0][r];
        float x1 = sa1[r] * sg1[r] * s4[1][r];
        Pr[w][l4 * 4 + r][t * 16 + l15]      = (short)f2bf(__builtin_fmaf(0.5f * x0, x0, x0));
        Pr[w][16 + l4 * 4 + r][t * 16 + l15] = (short)f2bf(__builtin_fmaf(0.5f * x1, x1, x1));
      }
    }
    // ---- PV as O^T = V^T·P^T; V-frags shared across both m-sets ----
#pragma unroll
    for (int ks = 0; ks < 2; ++ks) {
      short8 pf0 = *(const short8*)&Pr[w][l15][ks * 32 + l4 * 8];
      short8 pf1 = *(const short8*)&Pr[w][16 + l15][ks * 32 + l4 * 8];
      accD[0] = MFMA(ones, pf0, accD[0]);
      accD[1] = MFMA(ones, pf1, accD[1]);
#pragma unroll
      for (int jt = 0; jt < 4; ++jt) {
        short8 va = *(const short8*)&Vts[jt * 16 + l15][ks * 32 + l4 * 8];
        accO[0][jt] = MFMA(va, pf0, accO[0][jt]);
        accO[1][jt] = MFMA(va, pf1, accO[1][jt]);
      }
    }
  }

  // ---- write partials: num (bf16, packed j-quads) + den (f32) ----
  unsigned short* num = (unsigned short*)(ws + (split ? NUM1_OFF : NUM0_OFF));
  float* den = (float*)(ws + DEN_OFF);
#pragma unroll
  for (int s = 0; s < 2; ++s) {
    const int mrow = m0 + w * 32 + s * 16 + l15;
    if (l4 == 0)
      den[((size_t)split * 8 + h) * 2048 + mrow] = accD[s][0];
#pragma unroll
    for (int jt = 0; jt < 4; ++jt) {
      uint2 pw;
      pw.x = pack2(accO[s][jt][0], accO[s][jt][1]);
      pw.y = pack2(accO[s][jt][2], accO[s][jt][3]);
      *(uint2*)(num + (size_t)mrow * 512 + h * 64 + jt * 16 + l4 * 4) = pw;
    }
  }
}

// out[m][c] = (Vsum[c] + num0+num1) / (2048 + den0+den1), c = h*64+j
__global__ __launch_bounds__(256)
void combine_kernel(const bf16* __restrict__ ws, float* __restrict__ out)
{
  const unsigned short* num0 = (const unsigned short*)(ws + NUM0_OFF);
  const unsigned short* num1 = (const unsigned short*)(ws + NUM1_OFF);
  const float* den = (const float*)(ws + DEN_OFF);
  const float* vs  = (const float*)(ws + VSUM_OFF);
  int idx = blockIdx.x * 256 + threadIdx.x;
  int m = idx >> 9, c = idx & 511, h = c >> 6;
  float d = 2048.0f + den[(size_t)h * 2048 + m] + den[(size_t)(8 + h) * 2048 + m];
  float n = vs[c] + b2f(num0[idx]) + b2f(num1[idx]);
  out[idx] = n / d;
}

extern "C" void kernel_launch(void* const* d_in, const int* in_sizes, int n_in,
                              void* d_out, int out_size, void* d_ws, size_t ws_size,
                              hipStream_t stream) {
  const float* first_app  = (const float*)d_in[0];
  const float* first_pos  = (const float*)d_in[1];
  const float* second_app = (const float*)d_in[2];
  const float* second_pos = (const float*)d_in[3];
  const float* WK  = (const float*)d_in[4];
  const float* bK  = (const float*)d_in[5];
  const float* WQ  = (const float*)d_in[6];
  const float* bQ  = (const float*)d_in[7];
  const float* WV  = (const float*)d_in[8];
  const float* bV  = (const float*)d_in[9];
  const float* WG1 = (const float*)d_in[10];
  const float* bG1 = (const float*)d_in[11];
  const float* WG2 = (const float*)d_in[12];
  const float* bG2 = (const float*)d_in[13];

  bf16* ws = (bf16*)d_ws;

  wtrans_kernel<<<dim3(32, 16, 5), 256, 0, stream>>>(WK, WQ, WG1, WG2, WV, ws);
  proj_mfma_kernel<<<dim3(8, 16, 5), 256, 0, stream>>>(
      first_app, first_pos, second_app, second_pos, bK, bQ, bG1, bG2, bV, ws);
  vsum_kernel<<<dim3(8), 256, 0, stream>>>(ws + VT_OFF, (float*)(ws + VSUM_OFF));
  attn_mfma_kernel<<<dim3(16, 8, 2), 256, 0, stream>>>(
      ws + KB_OFF, ws + G1_OFF, ws + VT_OFF, ws + QB_OFF, ws + G2_OFF, ws);
  combine_kernel<<<dim3(4096), 256, 0, stream>>>(ws, (float*)d_out);
}

// Round 8
// 179.715 us; speedup vs baseline: 1.0685x; 1.0685x over previous
//
#include <hip/hip_runtime.h>
#include <hip/hip_bf16.h>

typedef __hip_bfloat16 bf16;
typedef __attribute__((ext_vector_type(8))) short short8;   // 8 bf16 = one MFMA A/B frag
typedef __attribute__((ext_vector_type(4))) float f32x4;    // MFMA C/D frag

#define MFMA(a, b, c) __builtin_amdgcn_mfma_f32_16x16x32_bf16(a, b, c, 0, 0, 0)

static __device__ __forceinline__ float b2f(unsigned short u) {
  union { unsigned u; float f; } t; t.u = ((unsigned)u) << 16; return t.f;
}
static __device__ __forceinline__ unsigned short f2bf(float f) {
  union { float f; unsigned u; } t; t.f = f;
  unsigned r = t.u + 0x7fffu + ((t.u >> 16) & 1u);   // RNE
  return (unsigned short)(r >> 16);
}
static __device__ __forceinline__ unsigned pack2(float a, float b) {
  return (unsigned)f2bf(a) | ((unsigned)f2bf(b) << 16);
}

// ---- workspace layout (bf16 element offsets) ----
#define KB_OFF   ((size_t)0)          // K  [2048][1024]
#define QB_OFF   ((size_t)2097152)    // Q  [2048][1024]
#define G1_OFF   ((size_t)4194304)    // G1 [2048][1024]
#define G2_OFF   ((size_t)6291456)    // G2 [2048][1024]
#define VT_OFF   ((size_t)8388608)    // V^T [512][2048]
#define WT_BASE  ((size_t)9437184)
#define WTK_OFF  (WT_BASE)                       // [1024][512]
#define WTQ_OFF  (WT_BASE + (size_t)524288)
#define WTG1_OFF (WT_BASE + (size_t)1048576)
#define WTG2_OFF (WT_BASE + (size_t)1572864)
#define WTV_OFF  (WT_BASE + (size_t)2097152)     // [512][512]
// After proj, WT region is dead -> reuse for attention partials (n-split 4):
#define NUM0_OFF (WT_BASE)                        // bf16 [2048][512] each
#define NUM1_OFF (WT_BASE + (size_t)1048576)
#define NUM2_OFF (WT_BASE + (size_t)2097152)
#define NUM3_OFF (WT_BASE + (size_t)3145728)
#define DEN_OFF  (WT_BASE + (size_t)4194304)      // f32 [4][8][2048]
// total ws: 13,762,560 bf16 elems = 27.5 MB

// Transpose + convert W[k][n] fp32 -> Wt[n][k] bf16, all 5 weights in one launch.
__global__ __launch_bounds__(256)
void wtrans_kernel(const float* __restrict__ WK, const float* __restrict__ WQ,
                   const float* __restrict__ WG1, const float* __restrict__ WG2,
                   const float* __restrict__ WV, bf16* __restrict__ ws)
{
  __shared__ float T[32][33];
  const float* W; unsigned short* Wt; int N;
  switch (blockIdx.z) {
    case 0:  W = WK;  Wt = (unsigned short*)(ws + WTK_OFF);  N = 1024; break;
    case 1:  W = WQ;  Wt = (unsigned short*)(ws + WTQ_OFF);  N = 1024; break;
    case 2:  W = WG1; Wt = (unsigned short*)(ws + WTG1_OFF); N = 1024; break;
    case 3:  W = WG2; Wt = (unsigned short*)(ws + WTG2_OFF); N = 1024; break;
    default: W = WV;  Wt = (unsigned short*)(ws + WTV_OFF);  N = 512;  break;
  }
  int n0 = blockIdx.x * 32, k0 = blockIdx.y * 32;
  if (n0 >= N) return;
  int tid = threadIdx.x;
  int kk = tid >> 3, nn = (tid & 7) * 4;
  float4 v = *(const float4*)(W + (size_t)(k0 + kk) * N + n0 + nn);
  T[kk][nn] = v.x; T[kk][nn + 1] = v.y; T[kk][nn + 2] = v.z; T[kk][nn + 3] = v.w;
  __syncthreads();
  int n2 = tid >> 3, k2 = (tid & 7) * 4;
  uint2 pw;
  pw.x = pack2(T[k2][n2],     T[k2 + 1][n2]);
  pw.y = pack2(T[k2 + 2][n2], T[k2 + 3][n2]);
  *(uint2*)(Wt + (size_t)(n0 + n2) * 512 + k0 + k2) = pw;
}

// Batched MFMA projection GEMM (verified round 4).
__global__ __launch_bounds__(256)
void proj_mfma_kernel(const float* __restrict__ fa, const float* __restrict__ fp,
                      const float* __restrict__ sa, const float* __restrict__ sp,
                      const float* __restrict__ bKp, const float* __restrict__ bQp,
                      const float* __restrict__ bG1p, const float* __restrict__ bG2p,
                      const float* __restrict__ bVp, bf16* __restrict__ ws)
{
  __shared__ short Xs[128][40];
  __shared__ short Wsh[128][40];
  const float* X; const unsigned short* Wt; const float* bias; unsigned short* C;
  int N; bool trans = false;
  switch (blockIdx.z) {
    case 0:  X = fa; Wt = (const unsigned short*)(ws + WTK_OFF);  bias = bKp;  C = (unsigned short*)(ws + KB_OFF); N = 1024; break;
    case 1:  X = sa; Wt = (const unsigned short*)(ws + WTQ_OFF);  bias = bQp;  C = (unsigned short*)(ws + QB_OFF); N = 1024; break;
    case 2:  X = fp; Wt = (const unsigned short*)(ws + WTG1_OFF); bias = bG1p; C = (unsigned short*)(ws + G1_OFF); N = 1024; break;
    case 3:  X = sp; Wt = (const unsigned short*)(ws + WTG2_OFF); bias = bG2p; C = (unsigned short*)(ws + G2_OFF); N = 1024; break;
    default: X = fa; Wt = (const unsigned short*)(ws + WTV_OFF);  bias = bVp;  C = (unsigned short*)(ws + VT_OFF); N = 512; trans = true; break;
  }
  const int n0 = blockIdx.x * 128;
  if (n0 >= N) return;
  const int m0 = blockIdx.y * 128;
  const int tid = threadIdx.x;
  const int w = tid >> 6, l = tid & 63, l15 = l & 15, l4 = l >> 4;
  const int wm = (w & 1) * 64, wn = (w >> 1) * 64;
  const int srow = tid >> 1, shalf = (tid & 1) * 16;

  const float* xp = X + (size_t)(m0 + srow) * 512 + shalf;
  const unsigned short* wp = Wt + (size_t)(n0 + srow) * 512 + shalf;

  const f32x4 zero = {0.f, 0.f, 0.f, 0.f};
  f32x4 acc[4][4];
#pragma unroll
  for (int i = 0; i < 4; ++i)
#pragma unroll
    for (int j = 0; j < 4; ++j) acc[i][j] = zero;

  float4 px[4]; uint4 pw0, pw1;
  auto ldg = [&](int kc) {
    px[0] = *(const float4*)(xp + kc);
    px[1] = *(const float4*)(xp + kc + 4);
    px[2] = *(const float4*)(xp + kc + 8);
    px[3] = *(const float4*)(xp + kc + 12);
    pw0 = *(const uint4*)(wp + kc);
    pw1 = *(const uint4*)(wp + kc + 8);
  };
  ldg(0);

  for (int kc = 0; kc < 512; kc += 32) {
    __syncthreads();
    uint4 xa, xb;
    xa.x = pack2(px[0].x, px[0].y); xa.y = pack2(px[0].z, px[0].w);
    xa.z = pack2(px[1].x, px[1].y); xa.w = pack2(px[1].z, px[1].w);
    xb.x = pack2(px[2].x, px[2].y); xb.y = pack2(px[2].z, px[2].w);
    xb.z = pack2(px[3].x, px[3].y); xb.w = pack2(px[3].z, px[3].w);
    *(uint4*)&Xs[srow][shalf]      = xa;
    *(uint4*)&Xs[srow][shalf + 8]  = xb;
    *(uint4*)&Wsh[srow][shalf]     = pw0;
    *(uint4*)&Wsh[srow][shalf + 8] = pw1;
    __syncthreads();
    if (kc + 32 < 512) ldg(kc + 32);

    short8 xf[4], wf[4];
#pragma unroll
    for (int t = 0; t < 4; ++t) {
      xf[t] = *(const short8*)&Xs[wm + t * 16 + l15][l4 * 8];
      wf[t] = *(const short8*)&Wsh[wn + t * 16 + l15][l4 * 8];
    }
    if (!trans) {
#pragma unroll
      for (int i = 0; i < 4; ++i)
#pragma unroll
        for (int j = 0; j < 4; ++j)
          acc[i][j] = MFMA(wf[i], xf[j], acc[i][j]);   // D[n][m]
    } else {
#pragma unroll
      for (int i = 0; i < 4; ++i)
#pragma unroll
        for (int j = 0; j < 4; ++j)
          acc[i][j] = MFMA(xf[i], wf[j], acc[i][j]);   // D[m][n]
    }
  }

  if (!trans) {
#pragma unroll
    for (int tn = 0; tn < 4; ++tn) {
      float4 b4 = *(const float4*)(bias + n0 + wn + tn * 16 + l4 * 4);
#pragma unroll
      for (int tm = 0; tm < 4; ++tm) {
        uint2 pw;
        pw.x = pack2(acc[tn][tm][0] + b4.x, acc[tn][tm][1] + b4.y);
        pw.y = pack2(acc[tn][tm][2] + b4.z, acc[tn][tm][3] + b4.w);
        *(uint2*)(C + (size_t)(m0 + wm + tm * 16 + l15) * N + n0 + wn + tn * 16 + l4 * 4) = pw;
      }
    }
  } else {
#pragma unroll
    for (int tn = 0; tn < 4; ++tn) {
      float bn = bias[n0 + wn + tn * 16 + l15];
#pragma unroll
      for (int tm = 0; tm < 4; ++tm) {
        uint2 pw;
        pw.x = pack2(acc[tm][tn][0] + bn, acc[tm][tn][1] + bn);
        pw.y = pack2(acc[tm][tn][2] + bn, acc[tm][tn][3] + bn);
        *(uint2*)(C + (size_t)(n0 + wn + tn * 16 + l15) * 2048 + m0 + wm + tm * 16 + l4 * 4) = pw;
      }
    }
  }
}

// MFMA fused attention: m=32/wave (amortized LDS, proven by conflict counter),
// n-split=4 -> grid 512 = 2 blocks/CU = 2 waves/SIMD (round-7 regression was
// 1 wave/SIMD latency exposure). Per-split sumV folded in via ones-B MFMAs
// (replaces the 8-block vsum_kernel). Partial num/den to ws; combine divides.
__global__ __launch_bounds__(256)
void attn_mfma_kernel(const bf16* __restrict__ Kb, const bf16* __restrict__ G1b,
                      const bf16* __restrict__ Vtg, const bf16* __restrict__ Qb,
                      const bf16* __restrict__ G2b, bf16* __restrict__ ws)
{
  __shared__ short Ks[64][136];    // stride 272B = 17 quads: balanced b128
  __shared__ short G1s[64][136];
  __shared__ short Vts[64][72];    // V^T[j][n], stride 144B
  __shared__ short Pr[4][32][72];  // per-wave P row-major [m 0..31][n]
  // LDS total = 62464 B -> 2 blocks/CU (124928 < 163840)

  const int tid = threadIdx.x;
  const int w   = tid >> 6;
  const int l   = tid & 63;
  const int l15 = l & 15;
  const int l4  = l >> 4;
  const int h   = blockIdx.y;
  const int m0  = blockIdx.x * 128;
  const int split = blockIdx.z;

  // ---- persistent Q/G2 A-fragments: 2 sets (rows w*32 + s*16 + l15) ----
  short8 qf[2][4], gf[2][4];
#pragma unroll
  for (int s = 0; s < 2; ++s) {
    const size_t ro = (size_t)(m0 + w * 32 + s * 16 + l15) * 1024 + h * 128 + l4 * 8;
#pragma unroll
    for (int kk = 0; kk < 4; ++kk) {
      qf[s][kk] = *(const short8*)(Qb + ro + kk * 32);
      gf[s][kk] = *(const short8*)(G2b + ro + kk * 32);
    }
  }
  // ---- row norms -> per-row scale, broadcast to C/D row positions ----
  float s4[2][4];
#pragma unroll
  for (int s = 0; s < 2; ++s) {
    float sq = 0.f, sg = 0.f;
#pragma unroll
    for (int kk = 0; kk < 4; ++kk)
#pragma unroll
      for (int j = 0; j < 8; ++j) {
        float q = b2f((unsigned short)qf[s][kk][j]);
        float g = b2f((unsigned short)gf[s][kk][j]);
        sq += q * q; sg += g * g;
      }
    sq += __shfl_xor(sq, 16, 64); sq += __shfl_xor(sq, 32, 64);
    sg += __shfl_xor(sg, 16, 64); sg += __shfl_xor(sg, 32, 64);
    float sc = rsqrtf(sq) * rsqrtf(sg) * (1.0f / 16384.0f);
#pragma unroll
    for (int r = 0; r < 4; ++r) s4[s][r] = __shfl(sc, l4 * 4 + r, 64);
  }

  const int r0 = tid >> 3, c0 = (tid & 7) * 16;   // K/G1 staging map
  const int jv = tid >> 2, nv = (tid & 3) * 16;   // Vt staging map

  short8 pk[4], pg[4], pv0, pv1;
  auto load_tile = [&](int nt) {       // nt in global 64-units
    const int n0 = nt * 64;
    const bf16* kp = Kb  + (size_t)(n0 + r0) * 1024 + h * 128 + c0;
    const bf16* gp = G1b + (size_t)(n0 + r0) * 1024 + h * 128 + c0;
    pk[0] = *(const short8*)(kp);
    pk[1] = *(const short8*)(kp + 8);
    pk[2] = *(const short8*)(kp + 32 * 1024);
    pk[3] = *(const short8*)(kp + 32 * 1024 + 8);
    pg[0] = *(const short8*)(gp);
    pg[1] = *(const short8*)(gp + 8);
    pg[2] = *(const short8*)(gp + 32 * 1024);
    pg[3] = *(const short8*)(gp + 32 * 1024 + 8);
    const bf16* vp = Vtg + (size_t)(h * 64 + jv) * 2048 + n0 + nv;
    pv0 = *(const short8*)(vp);
    pv1 = *(const short8*)(vp + 8);
  };
  const int ntbase = split * 8;
  load_tile(ntbase);

  const f32x4 zero = {0.f, 0.f, 0.f, 0.f};
  f32x4 accO[2][4], accV[4], accD[2] = {zero, zero};
#pragma unroll
  for (int t = 0; t < 4; ++t) accV[t] = zero;
#pragma unroll
  for (int s = 0; s < 2; ++s)
#pragma unroll
    for (int t = 0; t < 4; ++t) accO[s][t] = zero;

  short8 ones;
#pragma unroll
  for (int j = 0; j < 8; ++j) ones[j] = (short)0x3F80;  // bf16 1.0

  for (int nt = 0; nt < 8; ++nt) {
    __syncthreads();
    *(short8*)&Ks[r0][c0]           = pk[0];
    *(short8*)&Ks[r0][c0 + 8]       = pk[1];
    *(short8*)&Ks[r0 + 32][c0]      = pk[2];
    *(short8*)&Ks[r0 + 32][c0 + 8]  = pk[3];
    *(short8*)&G1s[r0][c0]          = pg[0];
    *(short8*)&G1s[r0][c0 + 8]      = pg[1];
    *(short8*)&G1s[r0 + 32][c0]     = pg[2];
    *(short8*)&G1s[r0 + 32][c0 + 8] = pg[3];
    *(short8*)&Vts[jv][nv]          = pv0;
    *(short8*)&Vts[jv][nv + 8]      = pv1;
    __syncthreads();
    if (nt + 1 < 8) load_tile(ntbase + nt + 1);   // prefetch overlaps compute

    // ---- scores: each K/G1 B-frag read feeds 2 MFMAs (2 m-sets) ----
#pragma unroll
    for (int t = 0; t < 4; ++t) {
      f32x4 sa0 = zero, sa1 = zero, sg0 = zero, sg1 = zero;
#pragma unroll
      for (int kk = 0; kk < 4; ++kk) {
        short8 kbf = *(const short8*)&Ks[t * 16 + l15][kk * 32 + l4 * 8];
        sa0 = MFMA(qf[0][kk], kbf, sa0);
        sa1 = MFMA(qf[1][kk], kbf, sa1);
        short8 gbf = *(const short8*)&G1s[t * 16 + l15][kk * 32 + l4 * 8];
        sg0 = MFMA(gf[0][kk], gbf, sg0);
        sg1 = MFMA(gf[1][kk], gbf, sg1);
      }
      // P' = x + x^2/2 (|x|~1e-4), bf16, per-wave row-major scratch
#pragma unroll
      for (int r = 0; r < 4; ++r) {
        float x0 = sa0[r] * sg0[r] * s4[0][r];
        float x1 = sa1[r] * sg1[r] * s4[1][r];
        Pr[w][l4 * 4 + r][t * 16 + l15]      = (short)f2bf(__builtin_fmaf(0.5f * x0, x0, x0));
        Pr[w][16 + l4 * 4 + r][t * 16 + l15] = (short)f2bf(__builtin_fmaf(0.5f * x1, x1, x1));
      }
    }
    // ---- PV as O^T = V^T·P^T; V-frags shared across both m-sets; sumV via
    // ones-B MFMA (D[j][*] = sum_n V^T[j][n], same for all m columns) ----
#pragma unroll
    for (int ks = 0; ks < 2; ++ks) {
      short8 pf0 = *(const short8*)&Pr[w][l15][ks * 32 + l4 * 8];
      short8 pf1 = *(const short8*)&Pr[w][16 + l15][ks * 32 + l4 * 8];
      accD[0] = MFMA(ones, pf0, accD[0]);
      accD[1] = MFMA(ones, pf1, accD[1]);
#pragma unroll
      for (int jt = 0; jt < 4; ++jt) {
        short8 va = *(const short8*)&Vts[jt * 16 + l15][ks * 32 + l4 * 8];
        accO[0][jt] = MFMA(va, pf0, accO[0][jt]);
        accO[1][jt] = MFMA(va, pf1, accO[1][jt]);
        accV[jt]    = MFMA(va, ones, accV[jt]);
      }
    }
  }

  // ---- write partials: num = accO + sumV (bf16, packed j-quads), den (f32) ----
  size_t numoff;
  switch (split) {
    case 0:  numoff = NUM0_OFF; break;
    case 1:  numoff = NUM1_OFF; break;
    case 2:  numoff = NUM2_OFF; break;
    default: numoff = NUM3_OFF; break;
  }
  unsigned short* num = (unsigned short*)(ws + numoff);
  float* den = (float*)(ws + DEN_OFF);
#pragma unroll
  for (int s = 0; s < 2; ++s) {
    const int mrow = m0 + w * 32 + s * 16 + l15;
    if (l4 == 0)
      den[((size_t)split * 8 + h) * 2048 + mrow] = accD[s][0];
#pragma unroll
    for (int jt = 0; jt < 4; ++jt) {
      uint2 pw;
      pw.x = pack2(accO[s][jt][0] + accV[jt][0], accO[s][jt][1] + accV[jt][1]);
      pw.y = pack2(accO[s][jt][2] + accV[jt][2], accO[s][jt][3] + accV[jt][3]);
      *(uint2*)(num + (size_t)mrow * 512 + h * 64 + jt * 16 + l4 * 4) = pw;
    }
  }
}

// out[m][c] = sum_s num_s / (2048 + sum_s den_s), c = h*64+j
__global__ __launch_bounds__(256)
void combine_kernel(const bf16* __restrict__ ws, float* __restrict__ out)
{
  const unsigned short* num0 = (const unsigned short*)(ws + NUM0_OFF);
  const unsigned short* num1 = (const unsigned short*)(ws + NUM1_OFF);
  const unsigned short* num2 = (const unsigned short*)(ws + NUM2_OFF);
  const unsigned short* num3 = (const unsigned short*)(ws + NUM3_OFF);
  const float* den = (const float*)(ws + DEN_OFF);
  int idx = blockIdx.x * 256 + threadIdx.x;
  int m = idx >> 9, c = idx & 511, h = c >> 6;
  float d = 2048.0f + den[(size_t)h * 2048 + m]
                    + den[(size_t)(8 + h) * 2048 + m]
                    + den[(size_t)(16 + h) * 2048 + m]
                    + den[(size_t)(24 + h) * 2048 + m];
  float n = b2f(num0[idx]) + b2f(num1[idx]) + b2f(num2[idx]) + b2f(num3[idx]);
  out[idx] = n / d;
}

extern "C" void kernel_launch(void* const* d_in, const int* in_sizes, int n_in,
                              void* d_out, int out_size, void* d_ws, size_t ws_size,
                              hipStream_t stream) {
  const float* first_app  = (const float*)d_in[0];
  const float* first_pos  = (const float*)d_in[1];
  const float* second_app = (const float*)d_in[2];
  const float* second_pos = (const float*)d_in[3];
  const float* WK  = (const float*)d_in[4];
  const float* bK  = (const float*)d_in[5];
  const float* WQ  = (const float*)d_in[6];
  const float* bQ  = (const float*)d_in[7];
  const float* WV  = (const float*)d_in[8];
  const float* bV  = (const float*)d_in[9];
  const float* WG1 = (const float*)d_in[10];
  const float* bG1 = (const float*)d_in[11];
  const float* WG2 = (const float*)d_in[12];
  const float* bG2 = (const float*)d_in[13];

  bf16* ws = (bf16*)d_ws;

  wtrans_kernel<<<dim3(32, 16, 5), 256, 0, stream>>>(WK, WQ, WG1, WG2, WV, ws);
  proj_mfma_kernel<<<dim3(8, 16, 5), 256, 0, stream>>>(
      first_app, first_pos, second_app, second_pos, bK, bQ, bG1, bG2, bV, ws);
  attn_mfma_kernel<<<dim3(16, 8, 4), 256, 0, stream>>>(
      ws + KB_OFF, ws + G1_OFF, ws + VT_OFF, ws + QB_OFF, ws + G2_OFF, ws);
  combine_kernel<<<dim3(4096), 256, 0, stream>>>(ws, (float*)d_out);
}

// Round 9
// 177.512 us; speedup vs baseline: 1.0818x; 1.0124x over previous
//
#include <hip/hip_runtime.h>
#include <hip/hip_bf16.h>

typedef __hip_bfloat16 bf16;
typedef __attribute__((ext_vector_type(8))) short short8;   // 8 bf16 = one MFMA A/B frag
typedef __attribute__((ext_vector_type(4))) float f32x4;    // MFMA C/D frag

#define MFMA(a, b, c) __builtin_amdgcn_mfma_f32_16x16x32_bf16(a, b, c, 0, 0, 0)

static __device__ __forceinline__ float b2f(unsigned short u) {
  union { unsigned u; float f; } t; t.u = ((unsigned)u) << 16; return t.f;
}
static __device__ __forceinline__ unsigned short f2bf(float f) {
  union { float f; unsigned u; } t; t.f = f;
  unsigned r = t.u + 0x7fffu + ((t.u >> 16) & 1u);   // RNE
  return (unsigned short)(r >> 16);
}
static __device__ __forceinline__ unsigned pack2(float a, float b) {
  return (unsigned)f2bf(a) | ((unsigned)f2bf(b) << 16);
}

// ---- workspace layout (bf16 element offsets) ----
#define KB_OFF   ((size_t)0)          // K  [2048][1024]
#define QB_OFF   ((size_t)2097152)    // Q  [2048][1024]
#define G1_OFF   ((size_t)4194304)    // G1 [2048][1024]
#define G2_OFF   ((size_t)6291456)    // G2 [2048][1024]
#define VT_OFF   ((size_t)8388608)    // V^T [512][2048]
#define WT_BASE  ((size_t)9437184)
#define WTK_OFF  (WT_BASE)                       // [1024][512]
#define WTQ_OFF  (WT_BASE + (size_t)524288)
#define WTG1_OFF (WT_BASE + (size_t)1048576)
#define WTG2_OFF (WT_BASE + (size_t)1572864)
#define WTV_OFF  (WT_BASE + (size_t)2097152)     // [512][512]
// After proj, WT region is dead -> reuse for attention partials (n-split 4):
#define NUM0_OFF (WT_BASE)                        // bf16 [2048][512] each
#define NUM1_OFF (WT_BASE + (size_t)1048576)
#define NUM2_OFF (WT_BASE + (size_t)2097152)
#define NUM3_OFF (WT_BASE + (size_t)3145728)
#define DEN_OFF  (WT_BASE + (size_t)4194304)      // f32 [4][8][2048]
// total ws: 13,762,560 bf16 elems = 27.5 MB

// Transpose + convert W[k][n] fp32 -> Wt[n][k] bf16, all 5 weights in one launch.
__global__ __launch_bounds__(256)
void wtrans_kernel(const float* __restrict__ WK, const float* __restrict__ WQ,
                   const float* __restrict__ WG1, const float* __restrict__ WG2,
                   const float* __restrict__ WV, bf16* __restrict__ ws)
{
  __shared__ float T[32][33];
  const float* W; unsigned short* Wt; int N;
  switch (blockIdx.z) {
    case 0:  W = WK;  Wt = (unsigned short*)(ws + WTK_OFF);  N = 1024; break;
    case 1:  W = WQ;  Wt = (unsigned short*)(ws + WTQ_OFF);  N = 1024; break;
    case 2:  W = WG1; Wt = (unsigned short*)(ws + WTG1_OFF); N = 1024; break;
    case 3:  W = WG2; Wt = (unsigned short*)(ws + WTG2_OFF); N = 1024; break;
    default: W = WV;  Wt = (unsigned short*)(ws + WTV_OFF);  N = 512;  break;
  }
  int n0 = blockIdx.x * 32, k0 = blockIdx.y * 32;
  if (n0 >= N) return;
  int tid = threadIdx.x;
  int kk = tid >> 3, nn = (tid & 7) * 4;
  float4 v = *(const float4*)(W + (size_t)(k0 + kk) * N + n0 + nn);
  T[kk][nn] = v.x; T[kk][nn + 1] = v.y; T[kk][nn + 2] = v.z; T[kk][nn + 3] = v.w;
  __syncthreads();
  int n2 = tid >> 3, k2 = (tid & 7) * 4;
  uint2 pw;
  pw.x = pack2(T[k2][n2],     T[k2 + 1][n2]);
  pw.y = pack2(T[k2 + 2][n2], T[k2 + 3][n2]);
  *(uint2*)(Wt + (size_t)(n0 + n2) * 512 + k0 + k2) = pw;
}

// Batched MFMA projection GEMM (verified round 4).
__global__ __launch_bounds__(256)
void proj_mfma_kernel(const float* __restrict__ fa, const float* __restrict__ fp,
                      const float* __restrict__ sa, const float* __restrict__ sp,
                      const float* __restrict__ bKp, const float* __restrict__ bQp,
                      const float* __restrict__ bG1p, const float* __restrict__ bG2p,
                      const float* __restrict__ bVp, bf16* __restrict__ ws)
{
  __shared__ short Xs[128][40];
  __shared__ short Wsh[128][40];
  const float* X; const unsigned short* Wt; const float* bias; unsigned short* C;
  int N; bool trans = false;
  switch (blockIdx.z) {
    case 0:  X = fa; Wt = (const unsigned short*)(ws + WTK_OFF);  bias = bKp;  C = (unsigned short*)(ws + KB_OFF); N = 1024; break;
    case 1:  X = sa; Wt = (const unsigned short*)(ws + WTQ_OFF);  bias = bQp;  C = (unsigned short*)(ws + QB_OFF); N = 1024; break;
    case 2:  X = fp; Wt = (const unsigned short*)(ws + WTG1_OFF); bias = bG1p; C = (unsigned short*)(ws + G1_OFF); N = 1024; break;
    case 3:  X = sp; Wt = (const unsigned short*)(ws + WTG2_OFF); bias = bG2p; C = (unsigned short*)(ws + G2_OFF); N = 1024; break;
    default: X = fa; Wt = (const unsigned short*)(ws + WTV_OFF);  bias = bVp;  C = (unsigned short*)(ws + VT_OFF); N = 512; trans = true; break;
  }
  const int n0 = blockIdx.x * 128;
  if (n0 >= N) return;
  const int m0 = blockIdx.y * 128;
  const int tid = threadIdx.x;
  const int w = tid >> 6, l = tid & 63, l15 = l & 15, l4 = l >> 4;
  const int wm = (w & 1) * 64, wn = (w >> 1) * 64;
  const int srow = tid >> 1, shalf = (tid & 1) * 16;

  const float* xp = X + (size_t)(m0 + srow) * 512 + shalf;
  const unsigned short* wp = Wt + (size_t)(n0 + srow) * 512 + shalf;

  const f32x4 zero = {0.f, 0.f, 0.f, 0.f};
  f32x4 acc[4][4];
#pragma unroll
  for (int i = 0; i < 4; ++i)
#pragma unroll
    for (int j = 0; j < 4; ++j) acc[i][j] = zero;

  float4 px[4]; uint4 pw0, pw1;
  auto ldg = [&](int kc) {
    px[0] = *(const float4*)(xp + kc);
    px[1] = *(const float4*)(xp + kc + 4);
    px[2] = *(const float4*)(xp + kc + 8);
    px[3] = *(const float4*)(xp + kc + 12);
    pw0 = *(const uint4*)(wp + kc);
    pw1 = *(const uint4*)(wp + kc + 8);
  };
  ldg(0);

  for (int kc = 0; kc < 512; kc += 32) {
    __syncthreads();
    uint4 xa, xb;
    xa.x = pack2(px[0].x, px[0].y); xa.y = pack2(px[0].z, px[0].w);
    xa.z = pack2(px[1].x, px[1].y); xa.w = pack2(px[1].z, px[1].w);
    xb.x = pack2(px[2].x, px[2].y); xb.y = pack2(px[2].z, px[2].w);
    xb.z = pack2(px[3].x, px[3].y); xb.w = pack2(px[3].z, px[3].w);
    *(uint4*)&Xs[srow][shalf]      = xa;
    *(uint4*)&Xs[srow][shalf + 8]  = xb;
    *(uint4*)&Wsh[srow][shalf]     = pw0;
    *(uint4*)&Wsh[srow][shalf + 8] = pw1;
    __syncthreads();
    if (kc + 32 < 512) ldg(kc + 32);

    short8 xf[4], wf[4];
#pragma unroll
    for (int t = 0; t < 4; ++t) {
      xf[t] = *(const short8*)&Xs[wm + t * 16 + l15][l4 * 8];
      wf[t] = *(const short8*)&Wsh[wn + t * 16 + l15][l4 * 8];
    }
    if (!trans) {
#pragma unroll
      for (int i = 0; i < 4; ++i)
#pragma unroll
        for (int j = 0; j < 4; ++j)
          acc[i][j] = MFMA(wf[i], xf[j], acc[i][j]);   // D[n][m]
    } else {
#pragma unroll
      for (int i = 0; i < 4; ++i)
#pragma unroll
        for (int j = 0; j < 4; ++j)
          acc[i][j] = MFMA(xf[i], wf[j], acc[i][j]);   // D[m][n]
    }
  }

  if (!trans) {
#pragma unroll
    for (int tn = 0; tn < 4; ++tn) {
      float4 b4 = *(const float4*)(bias + n0 + wn + tn * 16 + l4 * 4);
#pragma unroll
      for (int tm = 0; tm < 4; ++tm) {
        uint2 pw;
        pw.x = pack2(acc[tn][tm][0] + b4.x, acc[tn][tm][1] + b4.y);
        pw.y = pack2(acc[tn][tm][2] + b4.z, acc[tn][tm][3] + b4.w);
        *(uint2*)(C + (size_t)(m0 + wm + tm * 16 + l15) * N + n0 + wn + tn * 16 + l4 * 4) = pw;
      }
    }
  } else {
#pragma unroll
    for (int tn = 0; tn < 4; ++tn) {
      float bn = bias[n0 + wn + tn * 16 + l15];
#pragma unroll
      for (int tm = 0; tm < 4; ++tm) {
        uint2 pw;
        pw.x = pack2(acc[tm][tn][0] + bn, acc[tm][tn][1] + bn);
        pw.y = pack2(acc[tm][tn][2] + bn, acc[tm][tn][3] + bn);
        *(uint2*)(C + (size_t)(n0 + wn + tn * 16 + l15) * 2048 + m0 + wm + tm * 16 + l4 * 4) = pw;
      }
    }
  }
}

// MFMA fused attention, occupancy-first: m=16/wave, Ntile=32, n-split=4 ->
// grid (32,8,4) = 1024 blocks x 256 thr = 262144 threads = 4 waves/SIMD.
// LDS 27.5 KB/block -> 4 blocks/CU. launch_bounds(256,4) caps VGPR at 128.
__global__ __launch_bounds__(256, 4)
void attn_mfma_kernel(const bf16* __restrict__ Kb, const bf16* __restrict__ G1b,
                      const bf16* __restrict__ Vtg, const bf16* __restrict__ Qb,
                      const bf16* __restrict__ G2b, bf16* __restrict__ ws)
{
  __shared__ short Ks[32][136];    // stride 272B = 17 quads: balanced b128
  __shared__ short G1s[32][136];
  __shared__ short Vts[64][42];    // V^T[j][n], stride 84B = 21 quads (odd)
  __shared__ short Pr[4][16][42];  // per-wave P row-major [m][n], stride 21 quads
  // LDS total = 8704*2 + 5376 + 5376 = 28160 B -> 4+ blocks/CU

  const int tid = threadIdx.x;
  const int w   = tid >> 6;
  const int l   = tid & 63;
  const int l15 = l & 15;
  const int l4  = l >> 4;
  const int h   = blockIdx.y;
  const int m0  = blockIdx.x * 64;
  const int split = blockIdx.z;

  // ---- persistent Q/G2 A-fragments (row m0 + w*16 + l15) ----
  short8 qf[4], gf[4];
  {
    const size_t ro = (size_t)(m0 + w * 16 + l15) * 1024 + h * 128 + l4 * 8;
#pragma unroll
    for (int kk = 0; kk < 4; ++kk) {
      qf[kk] = *(const short8*)(Qb + ro + kk * 32);
      gf[kk] = *(const short8*)(G2b + ro + kk * 32);
    }
  }
  // ---- row norms -> per-row scale, broadcast to C/D row positions ----
  float s4[4];
  {
    float sq = 0.f, sg = 0.f;
#pragma unroll
    for (int kk = 0; kk < 4; ++kk)
#pragma unroll
      for (int j = 0; j < 8; ++j) {
        float q = b2f((unsigned short)qf[kk][j]);
        float g = b2f((unsigned short)gf[kk][j]);
        sq += q * q; sg += g * g;
      }
    sq += __shfl_xor(sq, 16, 64); sq += __shfl_xor(sq, 32, 64);
    sg += __shfl_xor(sg, 16, 64); sg += __shfl_xor(sg, 32, 64);
    float sc = rsqrtf(sq) * rsqrtf(sg) * (1.0f / 16384.0f);
#pragma unroll
    for (int r = 0; r < 4; ++r) s4[r] = __shfl(sc, l4 * 4 + r, 64);
  }

  const int r0 = tid >> 3, c0 = (tid & 7) * 16;   // K/G1 staging: 32 rows x 128
  const int jv = tid >> 2, nv = (tid & 3) * 8;    // Vt staging: 64 rows x 32

  short8 pk[2], pg[2], pv0;
  auto load_tile = [&](int nt) {       // nt in global 32-units
    const int n0 = nt * 32;
    const bf16* kp = Kb  + (size_t)(n0 + r0) * 1024 + h * 128 + c0;
    const bf16* gp = G1b + (size_t)(n0 + r0) * 1024 + h * 128 + c0;
    pk[0] = *(const short8*)(kp);
    pk[1] = *(const short8*)(kp + 8);
    pg[0] = *(const short8*)(gp);
    pg[1] = *(const short8*)(gp + 8);
    pv0 = *(const short8*)(Vtg + (size_t)(h * 64 + jv) * 2048 + n0 + nv);
  };
  const int ntbase = split * 16;
  load_tile(ntbase);

  const f32x4 zero = {0.f, 0.f, 0.f, 0.f};
  f32x4 accO[4], accV[4], accD = zero;
#pragma unroll
  for (int t = 0; t < 4; ++t) { accO[t] = zero; accV[t] = zero; }

  short8 ones;
#pragma unroll
  for (int j = 0; j < 8; ++j) ones[j] = (short)0x3F80;  // bf16 1.0

  for (int nt = 0; nt < 16; ++nt) {
    __syncthreads();
    *(short8*)&Ks[r0][c0]      = pk[0];
    *(short8*)&Ks[r0][c0 + 8]  = pk[1];
    *(short8*)&G1s[r0][c0]     = pg[0];
    *(short8*)&G1s[r0][c0 + 8] = pg[1];
    *(short8*)&Vts[jv][nv]     = pv0;
    __syncthreads();
    if (nt + 1 < 16) load_tile(ntbase + nt + 1);   // prefetch overlaps compute

    // ---- scores: SA = Q·K^T, SG = G2·G1^T; D[m=l4*4+r][n=t*16+l15] ----
#pragma unroll
    for (int t = 0; t < 2; ++t) {
      f32x4 sa = zero, sg2 = zero;
#pragma unroll
      for (int kk = 0; kk < 4; ++kk) {
        short8 kbf = *(const short8*)&Ks[t * 16 + l15][kk * 32 + l4 * 8];
        sa = MFMA(qf[kk], kbf, sa);
        short8 gbf = *(const short8*)&G1s[t * 16 + l15][kk * 32 + l4 * 8];
        sg2 = MFMA(gf[kk], gbf, sg2);
      }
      // P' = x + x^2/2 (|x|~1e-4), bf16, per-wave row-major scratch [m][n]
#pragma unroll
      for (int r = 0; r < 4; ++r) {
        float x = sa[r] * sg2[r] * s4[r];
        Pr[w][l4 * 4 + r][t * 16 + l15] = (short)f2bf(__builtin_fmaf(0.5f * x, x, x));
      }
    }
    // ---- PV as O^T = V^T·P^T (K-dim = 32 = one MFMA); denom & sumV via ones ----
    {
      short8 pf = *(const short8*)&Pr[w][l15][l4 * 8];   // B[k=n][m=l15]
      accD = MFMA(ones, pf, accD);
#pragma unroll
      for (int jt = 0; jt < 4; ++jt) {
        short8 va = *(const short8*)&Vts[jt * 16 + l15][l4 * 8];  // A[j][n]
        accO[jt] = MFMA(va, pf, accO[jt]);
        accV[jt] = MFMA(va, ones, accV[jt]);
      }
    }
  }

  // ---- write partials: num = accO + sumV (bf16, packed j-quads), den (f32) ----
  size_t numoff;
  switch (split) {
    case 0:  numoff = NUM0_OFF; break;
    case 1:  numoff = NUM1_OFF; break;
    case 2:  numoff = NUM2_OFF; break;
    default: numoff = NUM3_OFF; break;
  }
  unsigned short* num = (unsigned short*)(ws + numoff);
  float* den = (float*)(ws + DEN_OFF);
  const int mrow = m0 + w * 16 + l15;
  if (l4 == 0)
    den[((size_t)split * 8 + h) * 2048 + mrow] = accD[0];
#pragma unroll
  for (int jt = 0; jt < 4; ++jt) {
    uint2 pw;
    pw.x = pack2(accO[jt][0] + accV[jt][0], accO[jt][1] + accV[jt][1]);
    pw.y = pack2(accO[jt][2] + accV[jt][2], accO[jt][3] + accV[jt][3]);
    *(uint2*)(num + (size_t)mrow * 512 + h * 64 + jt * 16 + l4 * 4) = pw;
  }
}

// out[m][c] = sum_s num_s / (2048 + sum_s den_s), c = h*64+j
__global__ __launch_bounds__(256)
void combine_kernel(const bf16* __restrict__ ws, float* __restrict__ out)
{
  const unsigned short* num0 = (const unsigned short*)(ws + NUM0_OFF);
  const unsigned short* num1 = (const unsigned short*)(ws + NUM1_OFF);
  const unsigned short* num2 = (const unsigned short*)(ws + NUM2_OFF);
  const unsigned short* num3 = (const unsigned short*)(ws + NUM3_OFF);
  const float* den = (const float*)(ws + DEN_OFF);
  int idx = blockIdx.x * 256 + threadIdx.x;
  int m = idx >> 9, c = idx & 511, h = c >> 6;
  float d = 2048.0f + den[(size_t)h * 2048 + m]
                    + den[(size_t)(8 + h) * 2048 + m]
                    + den[(size_t)(16 + h) * 2048 + m]
                    + den[(size_t)(24 + h) * 2048 + m];
  float n = b2f(num0[idx]) + b2f(num1[idx]) + b2f(num2[idx]) + b2f(num3[idx]);
  out[idx] = n / d;
}

extern "C" void kernel_launch(void* const* d_in, const int* in_sizes, int n_in,
                              void* d_out, int out_size, void* d_ws, size_t ws_size,
                              hipStream_t stream) {
  const float* first_app  = (const float*)d_in[0];
  const float* first_pos  = (const float*)d_in[1];
  const float* second_app = (const float*)d_in[2];
  const float* second_pos = (const float*)d_in[3];
  const float* WK  = (const float*)d_in[4];
  const float* bK  = (const float*)d_in[5];
  const float* WQ  = (const float*)d_in[6];
  const float* bQ  = (const float*)d_in[7];
  const float* WV  = (const float*)d_in[8];
  const float* bV  = (const float*)d_in[9];
  const float* WG1 = (const float*)d_in[10];
  const float* bG1 = (const float*)d_in[11];
  const float* WG2 = (const float*)d_in[12];
  const float* bG2 = (const float*)d_in[13];

  bf16* ws = (bf16*)d_ws;

  wtrans_kernel<<<dim3(32, 16, 5), 256, 0, stream>>>(WK, WQ, WG1, WG2, WV, ws);
  proj_mfma_kernel<<<dim3(8, 16, 5), 256, 0, stream>>>(
      first_app, first_pos, second_app, second_pos, bK, bQ, bG1, bG2, bV, ws);
  attn_mfma_kernel<<<dim3(32, 8, 4), 256, 0, stream>>>(
      ws + KB_OFF, ws + G1_OFF, ws + VT_OFF, ws + QB_OFF, ws + G2_OFF, ws);
  combine_kernel<<<dim3(4096), 256, 0, stream>>>(ws, (float*)d_out);
}